// Round 8
// baseline (781.531 us; speedup 1.0000x reference)
//
#include <hip/hip_runtime.h>
#include <math.h>

// ---------------- constants ----------------
#define FDIM 128          // F_IN == HEADS*C_HID == 128
#define NEG_SLOPE 0.2f
#define LP_ALPHA 0.5f
#define NGRAPHS 32
#define POOLF 384         // 3*128
#define MLP_H 256
#define OUT_F 128
#define POOL_CH 8         // chunks per (graph, source) in pooling

#define LRELU(z) ((z) > 0.0f ? (z) : NEG_SLOPE * (z))

// ---------------- CSR build ----------------
__global__ void count_deg_k(const int* __restrict__ dst, int* __restrict__ deg, int E) {
    int e = blockIdx.x * blockDim.x + threadIdx.x;
    if (e < E) atomicAdd(&deg[dst[e]], 1);
}

// ---- hierarchical exclusive scan over deg[N] (tiles of 1024) ----
__global__ __launch_bounds__(256) void scan_part_k(const int* __restrict__ deg,
                                                   int* __restrict__ tileSum, int N) {
    int b = blockIdx.x, t = threadIdx.x;
    int base = b * 1024 + t * 4;
    int v = 0;
    if (base + 3 < N) { int4 d = *(const int4*)(deg + base); v = d.x + d.y + d.z + d.w; }
    else if (base < N) {
        v = deg[base];
        if (base + 1 < N) v += deg[base + 1];
        if (base + 2 < N) v += deg[base + 2];
    }
#pragma unroll
    for (int off = 32; off > 0; off >>= 1) v += __shfl_xor(v, off, 64);
    __shared__ int ws[4];
    if ((t & 63) == 0) ws[t >> 6] = v;
    __syncthreads();
    if (t == 0) tileSum[b] = ws[0] + ws[1] + ws[2] + ws[3];
}

// single wave: exclusive scan of tile sums (nt <= 64)
__global__ void scan_tiles_k(const int* __restrict__ tileSum, int* __restrict__ tileOff, int nt) {
    int t = threadIdx.x;   // 64
    int v = (t < nt) ? tileSum[t] : 0;
    int incl = v;
#pragma unroll
    for (int off = 1; off < 64; off <<= 1) {
        int u = __shfl_up(incl, off, 64);
        if (t >= off) incl += u;
    }
    if (t < nt) tileOff[t] = incl - v;
}

// per-tile write-out of row_ptr + cursor copy (+ fused dinv); row_ptr[N] = E (known)
__global__ __launch_bounds__(256) void scan_write_k(const int* __restrict__ deg,
                                                    const int* __restrict__ tileOff,
                                                    int* __restrict__ row_ptr,
                                                    int* __restrict__ cursor,
                                                    float* __restrict__ dinv, int N, int E) {
    int b = blockIdx.x, t = threadIdx.x;
    int base = b * 1024 + t * 4;
    int d0 = 0, d1 = 0, d2 = 0, d3 = 0;
    if (base + 3 < N) { int4 d = *(const int4*)(deg + base); d0 = d.x; d1 = d.y; d2 = d.z; d3 = d.w; }
    else if (base < N) {
        d0 = deg[base];
        if (base + 1 < N) d1 = deg[base + 1];
        if (base + 2 < N) d2 = deg[base + 2];
    }
    int lsum = d0 + d1 + d2 + d3;
    int lane = t & 63, wv = t >> 6;
    int incl = lsum;
#pragma unroll
    for (int off = 1; off < 64; off <<= 1) {
        int u = __shfl_up(incl, off, 64);
        if (lane >= off) incl += u;
    }
    __shared__ int wsum[4];
    if (lane == 63) wsum[wv] = incl;
    __syncthreads();
    int woff = 0;
#pragma unroll
    for (int k = 0; k < 4; ++k) if (k < wv) woff += wsum[k];
    int off0 = tileOff[b] + woff + (incl - lsum);
    if (base < N)     { row_ptr[base]     = off0;                cursor[base]     = off0;
                        dinv[base]     = d0 > 0 ? 1.0f / sqrtf((float)d0) : 0.0f; }
    if (base + 1 < N) { row_ptr[base + 1] = off0 + d0;           cursor[base + 1] = off0 + d0;
                        dinv[base + 1] = d1 > 0 ? 1.0f / sqrtf((float)d1) : 0.0f; }
    if (base + 2 < N) { row_ptr[base + 2] = off0 + d0 + d1;      cursor[base + 2] = off0 + d0 + d1;
                        dinv[base + 2] = d2 > 0 ? 1.0f / sqrtf((float)d2) : 0.0f; }
    if (base + 3 < N) { row_ptr[base + 3] = off0 + d0 + d1 + d2; cursor[base + 3] = off0 + d0 + d1 + d2;
                        dinv[base + 3] = d3 > 0 ? 1.0f / sqrtf((float)d3) : 0.0f; }
    if (b == 0 && t == 0) row_ptr[N] = E;
}

// one random 8B nt-store per edge: {src, dinv[src]}; cursor gives absolute slot
__global__ void scatter_k(const int* __restrict__ src, const int* __restrict__ dst,
                          int* __restrict__ cursor, const float* __restrict__ dinv,
                          int2* __restrict__ elist, int E) {
    int e = blockIdx.x * blockDim.x + threadIdx.x;
    if (e >= E) return;
    int d = dst[e], s = src[e];
    int pos = atomicAdd(&cursor[d], 1);
    unsigned long long v = (unsigned int)s |
                           ((unsigned long long)(unsigned int)__float_as_int(dinv[s]) << 32);
    __builtin_nontemporal_store(v, (unsigned long long*)&elist[pos]);
}

// ---------------- graph boundaries: batch is SORTED -> binary search ----------------
__global__ void gbound_k(const int* __restrict__ batch, int* __restrict__ gb, int N) {
    int g = threadIdx.x;             // 0..NGRAPHS
    if (g > NGRAPHS) return;
    int lo = 0, hi = N;              // first index with batch[i] >= g
    while (lo < hi) {
        int mid = (lo + hi) >> 1;
        if (batch[mid] < g) lo = mid + 1; else hi = mid;
    }
    gb[g] = lo;
}

// ---------------- fused dual node GEMM: Yl = X@Wl, Yr = X@Wr ----------------
// 64 rows/block, 512 threads (8 waves -> ~24 waves/CU), 4x4x2 thread tile.
__global__ __launch_bounds__(512) void gemm128x2_k(const float* __restrict__ X,
                                                   const float* __restrict__ Wl,
                                                   const float* __restrict__ Wr,
                                                   float* __restrict__ Yl,
                                                   float* __restrict__ Yr, int N) {
    __shared__ float Xs[FDIM][68];        // [k][r], padded; 34.8 KB
    int t = threadIdx.x;
    int r0 = blockIdx.x * 64;
    for (int idx = t; idx < 64 * FDIM; idx += 512) {
        int k = idx & 127, r = idx >> 7;
        int row = r0 + r;
        Xs[k][r] = (row < N) ? X[(size_t)row * FDIM + k] : 0.0f;
    }
    __syncthreads();
    int tr = t >> 5;      // 0..15 (16 row-groups of 4 rows)
    int tc = t & 31;      // 0..31 (32 col-groups of 4 cols)
    float accl[4][4] = {{0.f}}, accr[4][4] = {{0.f}};
#pragma unroll 4
    for (int k = 0; k < FDIM; ++k) {
        float4 bl = *(const float4*)(Wl + k * FDIM + tc * 4);   // L1/L2-resident
        float4 br = *(const float4*)(Wr + k * FDIM + tc * 4);
        float4 a = *(const float4*)(&Xs[k][tr * 4]);            // broadcast within half-wave
        float av[4] = {a.x, a.y, a.z, a.w};
#pragma unroll
        for (int r = 0; r < 4; ++r) {
            accl[r][0] = fmaf(av[r], bl.x, accl[r][0]);
            accl[r][1] = fmaf(av[r], bl.y, accl[r][1]);
            accl[r][2] = fmaf(av[r], bl.z, accl[r][2]);
            accl[r][3] = fmaf(av[r], bl.w, accl[r][3]);
            accr[r][0] = fmaf(av[r], br.x, accr[r][0]);
            accr[r][1] = fmaf(av[r], br.y, accr[r][1]);
            accr[r][2] = fmaf(av[r], br.z, accr[r][2]);
            accr[r][3] = fmaf(av[r], br.w, accr[r][3]);
        }
    }
#pragma unroll
    for (int r = 0; r < 4; ++r) {
        int row = r0 + tr * 4 + r;
        if (row < N) {
            *(float4*)(Yl + (size_t)row * FDIM + tc * 4) =
                make_float4(accl[r][0], accl[r][1], accl[r][2], accl[r][3]);
            *(float4*)(Yr + (size_t)row * FDIM + tc * 4) =
                make_float4(accr[r][0], accr[r][1], accr[r][2], accr[r][3]);
        }
    }
}

// ---------------- GATv2 pull: quarter-wave edge groups ----------------
// wave = 1 node. qw = lane>>4 (4 edge streams), lq = lane&15 holds channels
// [8lq, 8lq+8) as 2 float4 (lq<8 -> head0, lq>=8 -> head1). Head-logit reduce
// = 3 shfls within 8-lane groups. 8 edges in flight (4 quarters x 2 states).
// Merge: in-lane, then butterfly shfl_xor 16/32 (softmax segment merges).
__global__ __launch_bounds__(256) void gat_pull_k(const float* __restrict__ xl,
                                                  const float* __restrict__ xr,
                                                  const int* __restrict__ row_ptr,
                                                  const int2* __restrict__ elist,
                                                  const float* __restrict__ att,
                                                  const float* __restrict__ bias,
                                                  float* __restrict__ out, int N) {
    int wid = threadIdx.x >> 6;
    int lane = threadIdx.x & 63;
    int qw = lane >> 4;
    int lq = lane & 15;
    int i = blockIdx.x * 4 + wid;
    if (i >= N) return;
    int cbase = 8 * lq;
    float4 at0 = *(const float4*)(att + cbase);
    float4 at1 = *(const float4*)(att + cbase + 4);
    size_t ibase = (size_t)i * FDIM + cbase;
    float4 xr0 = *(const float4*)(xr + ibase);
    float4 xr1 = *(const float4*)(xr + ibase + 4);
    float4 xs0 = *(const float4*)(xl + ibase);
    float4 xs1 = *(const float4*)(xl + ibase + 4);

    auto qdot = [&](float4 x0, float4 x1) {   // this head's logit (8-lane reduce)
        float v = LRELU(xr0.x + x0.x) * at0.x + LRELU(xr0.y + x0.y) * at0.y
                + LRELU(xr0.z + x0.z) * at0.z + LRELU(xr0.w + x0.w) * at0.w
                + LRELU(xr1.x + x1.x) * at1.x + LRELU(xr1.y + x1.y) * at1.y
                + LRELU(xr1.z + x1.z) * at1.z + LRELU(xr1.w + x1.w) * at1.w;
        v += __shfl_xor(v, 1, 64);
        v += __shfl_xor(v, 2, 64);
        v += __shfl_xor(v, 4, 64);
        return v;
    };

    const float4 z4 = make_float4(0.f, 0.f, 0.f, 0.f);
    // self-loop seeds quarter 0's state A
    float lself = qdot(xs0, xs1);
    bool q0 = (qw == 0);
    float mA = q0 ? lself : -INFINITY, sA = q0 ? 1.0f : 0.0f;
    float4 aA0 = q0 ? xs0 : z4, aA1 = q0 ? xs1 : z4;
    float mB = -INFINITY, sB = 0.0f;
    float4 aB0 = z4, aB1 = z4;

    int beg = row_ptr[i], end = row_ptr[i + 1];
    for (int p = beg; p < end; p += 8) {
        int i0 = p + qw, i1 = p + 4 + qw;
        bool v0 = i0 < end, v1 = i1 < end;
        int j0 = elist[min(i0, end - 1)].x;
        int j1 = elist[min(i1, end - 1)].x;
        const float* b0 = xl + (size_t)j0 * FDIM + cbase;
        const float* b1 = xl + (size_t)j1 * FDIM + cbase;
        float4 x00 = *(const float4*)(b0), x01 = *(const float4*)(b0 + 4);
        float4 x10 = *(const float4*)(b1), x11 = *(const float4*)(b1 + 4);
        float l0 = qdot(x00, x01);
        float l1 = qdot(x10, x11);
        if (v0) {
            float mn = fmaxf(mA, l0);
            float sc = __expf(mA - mn), pe = __expf(l0 - mn);  // mA=-inf -> sc=0
            sA = fmaf(sA, sc, pe);
            aA0.x = fmaf(aA0.x, sc, pe * x00.x); aA0.y = fmaf(aA0.y, sc, pe * x00.y);
            aA0.z = fmaf(aA0.z, sc, pe * x00.z); aA0.w = fmaf(aA0.w, sc, pe * x00.w);
            aA1.x = fmaf(aA1.x, sc, pe * x01.x); aA1.y = fmaf(aA1.y, sc, pe * x01.y);
            aA1.z = fmaf(aA1.z, sc, pe * x01.z); aA1.w = fmaf(aA1.w, sc, pe * x01.w);
            mA = mn;
        }
        if (v1) {
            float mn = fmaxf(mB, l1);
            float sc = __expf(mB - mn), pe = __expf(l1 - mn);
            sB = fmaf(sB, sc, pe);
            aB0.x = fmaf(aB0.x, sc, pe * x10.x); aB0.y = fmaf(aB0.y, sc, pe * x10.y);
            aB0.z = fmaf(aB0.z, sc, pe * x10.z); aB0.w = fmaf(aB0.w, sc, pe * x10.w);
            aB1.x = fmaf(aB1.x, sc, pe * x11.x); aB1.y = fmaf(aB1.y, sc, pe * x11.y);
            aB1.z = fmaf(aB1.z, sc, pe * x11.z); aB1.w = fmaf(aB1.w, sc, pe * x11.w);
            mB = mn;
        }
    }
    // in-lane merge B -> A (guard double -inf)
    {
        float mn = fmaxf(mA, mB);
        float cA = (mA == -INFINITY) ? 0.0f : __expf(mA - mn);
        float cB = (mB == -INFINITY) ? 0.0f : __expf(mB - mn);
        sA = sA * cA + sB * cB;
        aA0.x = aA0.x * cA + aB0.x * cB; aA0.y = aA0.y * cA + aB0.y * cB;
        aA0.z = aA0.z * cA + aB0.z * cB; aA0.w = aA0.w * cA + aB0.w * cB;
        aA1.x = aA1.x * cA + aB1.x * cB; aA1.y = aA1.y * cA + aB1.y * cB;
        aA1.z = aA1.z * cA + aB1.z * cB; aA1.w = aA1.w * cA + aB1.w * cB;
        mA = mn;
    }
    // butterfly across quarters (xor 16, then 32); same lq -> same head
#pragma unroll
    for (int mask = 16; mask <= 32; mask <<= 1) {
        float pm = __shfl_xor(mA, mask, 64);
        float ps = __shfl_xor(sA, mask, 64);
        float p0x = __shfl_xor(aA0.x, mask, 64), p0y = __shfl_xor(aA0.y, mask, 64);
        float p0z = __shfl_xor(aA0.z, mask, 64), p0w = __shfl_xor(aA0.w, mask, 64);
        float p1x = __shfl_xor(aA1.x, mask, 64), p1y = __shfl_xor(aA1.y, mask, 64);
        float p1z = __shfl_xor(aA1.z, mask, 64), p1w = __shfl_xor(aA1.w, mask, 64);
        float mn = fmaxf(mA, pm);
        float cA = (mA == -INFINITY) ? 0.0f : __expf(mA - mn);
        float cP = (pm == -INFINITY) ? 0.0f : __expf(pm - mn);
        sA = sA * cA + ps * cP;
        aA0.x = aA0.x * cA + p0x * cP; aA0.y = aA0.y * cA + p0y * cP;
        aA0.z = aA0.z * cA + p0z * cP; aA0.w = aA0.w * cA + p0w * cP;
        aA1.x = aA1.x * cA + p1x * cP; aA1.y = aA1.y * cA + p1y * cP;
        aA1.z = aA1.z * cA + p1z * cP; aA1.w = aA1.w * cA + p1w * cP;
        mA = mn;
    }
    if (qw == 0) {
        float inv = 1.0f / (sA + 1e-16f);
        float4 bv0 = *(const float4*)(bias + cbase);
        float4 bv1 = *(const float4*)(bias + cbase + 4);
        float z0 = aA0.x * inv + bv0.x, z1 = aA0.y * inv + bv0.y;
        float z2 = aA0.z * inv + bv0.z, z3 = aA0.w * inv + bv0.w;
        float z4_ = aA1.x * inv + bv1.x, z5 = aA1.y * inv + bv1.y;
        float z6 = aA1.z * inv + bv1.z, z7 = aA1.w * inv + bv1.w;
        float4 o0, o1;
        o0.x = (z0 > 0.f) ? z0 : (__expf(z0) - 1.f);
        o0.y = (z1 > 0.f) ? z1 : (__expf(z1) - 1.f);
        o0.z = (z2 > 0.f) ? z2 : (__expf(z2) - 1.f);
        o0.w = (z3 > 0.f) ? z3 : (__expf(z3) - 1.f);
        o1.x = (z4_ > 0.f) ? z4_ : (__expf(z4_) - 1.f);
        o1.y = (z5 > 0.f) ? z5 : (__expf(z5) - 1.f);
        o1.z = (z6 > 0.f) ? z6 : (__expf(z6) - 1.f);
        o1.w = (z7 > 0.f) ? z7 : (__expf(z7) - 1.f);
        *(float4*)(out + ibase) = o0;
        *(float4*)(out + ibase + 4) = o1;
    }
}

// ---------------- label propagation pull: half-wave edge pairing ----------------
__global__ __launch_bounds__(256) void lp_pull_k(const float* __restrict__ y,
                                                 const float* __restrict__ cur,
                                                 float* __restrict__ nxt,
                                                 const int* __restrict__ row_ptr,
                                                 const int2* __restrict__ elist,
                                                 const float* __restrict__ dinv, int N) {
    int wid = threadIdx.x >> 6, lane = threadIdx.x & 63;
    int half = lane >> 5, lh = lane & 31;
    int i = blockIdx.x * 4 + wid;
    if (i >= N) return;
    int beg = row_ptr[i], end = row_ptr[i + 1];
    float4 a0 = make_float4(0.f, 0.f, 0.f, 0.f), a1 = a0, a2 = a0, a3 = a0;
    for (int p = beg; p < end; p += 8) {
        int i0 = p + half, i1 = p + 2 + half, i2 = p + 4 + half, i3 = p + 6 + half;
        int2 e0 = elist[min(i0, end - 1)];
        int2 e1 = elist[min(i1, end - 1)];
        int2 e2 = elist[min(i2, end - 1)];
        int2 e3 = elist[min(i3, end - 1)];
        float w0 = (i0 < end) ? __int_as_float(e0.y) : 0.0f;
        float w1 = (i1 < end) ? __int_as_float(e1.y) : 0.0f;
        float w2 = (i2 < end) ? __int_as_float(e2.y) : 0.0f;
        float w3 = (i3 < end) ? __int_as_float(e3.y) : 0.0f;
        float4 x0 = *(const float4*)(cur + (size_t)e0.x * FDIM + 4 * lh);
        float4 x1 = *(const float4*)(cur + (size_t)e1.x * FDIM + 4 * lh);
        float4 x2 = *(const float4*)(cur + (size_t)e2.x * FDIM + 4 * lh);
        float4 x3 = *(const float4*)(cur + (size_t)e3.x * FDIM + 4 * lh);
        a0.x = fmaf(w0, x0.x, a0.x); a0.y = fmaf(w0, x0.y, a0.y);
        a0.z = fmaf(w0, x0.z, a0.z); a0.w = fmaf(w0, x0.w, a0.w);
        a1.x = fmaf(w1, x1.x, a1.x); a1.y = fmaf(w1, x1.y, a1.y);
        a1.z = fmaf(w1, x1.z, a1.z); a1.w = fmaf(w1, x1.w, a1.w);
        a2.x = fmaf(w2, x2.x, a2.x); a2.y = fmaf(w2, x2.y, a2.y);
        a2.z = fmaf(w2, x2.z, a2.z); a2.w = fmaf(w2, x2.w, a2.w);
        a3.x = fmaf(w3, x3.x, a3.x); a3.y = fmaf(w3, x3.y, a3.y);
        a3.z = fmaf(w3, x3.z, a3.z); a3.w = fmaf(w3, x3.w, a3.w);
    }
    float4 a;
    a.x = (a0.x + a1.x) + (a2.x + a3.x);
    a.y = (a0.y + a1.y) + (a2.y + a3.y);
    a.z = (a0.z + a1.z) + (a2.z + a3.z);
    a.w = (a0.w + a1.w) + (a2.w + a3.w);
    a.x += __shfl_xor(a.x, 32, 64);
    a.y += __shfl_xor(a.y, 32, 64);
    a.z += __shfl_xor(a.z, 32, 64);
    a.w += __shfl_xor(a.w, 32, 64);
    if (half == 0) {
        float di = dinv[i];
        size_t ibase = (size_t)i * FDIM + 4 * lh;
        float4 yv = *(const float4*)(y + ibase);
        float4 o;
        o.x = fminf(fmaxf(fmaf(LP_ALPHA * di, a.x, (1.0f - LP_ALPHA) * yv.x), 0.f), 1.f);
        o.y = fminf(fmaxf(fmaf(LP_ALPHA * di, a.y, (1.0f - LP_ALPHA) * yv.y), 0.f), 1.f);
        o.z = fminf(fmaxf(fmaf(LP_ALPHA * di, a.z, (1.0f - LP_ALPHA) * yv.z), 0.f), 1.f);
        o.w = fminf(fmaxf(fmaf(LP_ALPHA * di, a.w, (1.0f - LP_ALPHA) * yv.w), 0.f), 1.f);
        *(float4*)(nxt + ibase) = o;
    }
}

// ---------------- pooling: segmented (batch sorted), atomic-free ----------------
__global__ void pool_part_k(const float* __restrict__ x, const float* __restrict__ h1,
                            const float* __restrict__ h2, const int* __restrict__ gb,
                            float* __restrict__ part) {
    int g = blockIdx.x, si = blockIdx.y, ch = blockIdx.z;
    int t = threadIdx.x; // 128
    const float* s = (si == 0) ? x : ((si == 1) ? h1 : h2);
    int n0g = gb[g], n1g = gb[g + 1];
    int len = n1g - n0g;
    int per = (len + POOL_CH - 1) / POOL_CH;
    int n0 = n0g + ch * per;
    int n1 = min(n0 + per, n1g);
    float acc = 0.0f;
    for (int n = n0; n < n1; ++n) acc += s[(size_t)n * FDIM + t];
    part[(((g * 3 + si) << 3) + ch) * FDIM + t] = acc;
}

// ---------------- MLP ----------------
__global__ void mlp1_k(const float* __restrict__ part, const int* __restrict__ gb,
                       const float* __restrict__ W1, const float* __restrict__ b1,
                       float* __restrict__ h) {
    int g = blockIdx.x;     // 32
    int t = threadIdx.x;    // 256
    __shared__ float gm[POOLF];
    int cnt = gb[g + 1] - gb[g];
    float inv = 1.0f / fmaxf((float)cnt, 1.0f);
    for (int f = t; f < POOLF; f += 256) {
        int si = f >> 7, fl = f & 127;
        float s = 0.0f;
#pragma unroll
        for (int c = 0; c < POOL_CH; ++c)
            s += part[(((g * 3 + si) << 3) + c) * FDIM + fl];
        gm[f] = s * inv;
    }
    __syncthreads();
    float acc = b1[t];
    for (int k = 0; k < POOLF; ++k) acc = fmaf(gm[k], W1[k * MLP_H + t], acc);
    h[g * MLP_H + t] = fmaxf(acc, 0.0f);
}

__global__ void mlp2_k(const float* __restrict__ h, const float* __restrict__ W2,
                       const float* __restrict__ b2, float* __restrict__ out) {
    int g = blockIdx.x;     // 32
    int t = threadIdx.x;    // 128
    __shared__ float hs[MLP_H];
    for (int k = t; k < MLP_H; k += 128) hs[k] = h[g * MLP_H + k];
    __syncthreads();
    float acc = b2[t];
    for (int k = 0; k < MLP_H; ++k) acc = fmaf(hs[k], W2[k * OUT_F + t], acc);
    out[g * OUT_F + t] = acc;
}

// ---------------- launch ----------------
extern "C" void kernel_launch(void* const* d_in, const int* in_sizes, int n_in,
                              void* d_out, int out_size, void* d_ws, size_t ws_size,
                              hipStream_t stream) {
    const float* x    = (const float*)d_in[0];
    const int*   ei   = (const int*)d_in[1];
    const int*   batch= (const int*)d_in[2];
    const float* W_l1 = (const float*)d_in[3];
    const float* W_r1 = (const float*)d_in[4];
    const float* att1 = (const float*)d_in[5];
    const float* b1   = (const float*)d_in[6];
    const float* W_l2 = (const float*)d_in[7];
    const float* W_r2 = (const float*)d_in[8];
    const float* att2 = (const float*)d_in[9];
    const float* b2   = (const float*)d_in[10];
    const float* mW1  = (const float*)d_in[11];
    const float* mb1  = (const float*)d_in[12];
    const float* mW2  = (const float*)d_in[13];
    const float* mb2  = (const float*)d_in[14];
    float* out = (float*)d_out;

    const int N = in_sizes[2];
    const int E = in_sizes[1] / 2;
    const int* src = ei;
    const int* dst = ei + E;

    char* w = (char*)d_ws;
    auto alloc = [&](size_t bytes) -> char* {
        char* p = w;
        w += (bytes + 255) & ~(size_t)255;
        return p;
    };
    float* bufA = (float*)alloc((size_t)N * FDIM * 4);
    float* bufB = (float*)alloc((size_t)N * FDIM * 4);
    float* bufC = (float*)alloc((size_t)N * FDIM * 4);   // h1 lives here
    float* bufD = (float*)alloc((size_t)N * FDIM * 4);   // h2 lives here
    int* deg     = (int*)alloc((size_t)N * 4);
    int* cursor  = (int*)alloc((size_t)N * 4);
    int* row_lp  = (int*)alloc((size_t)(N + 1) * 4);
    int2* elist  = (int2*)alloc((size_t)E * 8);
    float* dinv  = (float*)alloc((size_t)N * 4);
    int* gb      = (int*)alloc((size_t)(NGRAPHS + 1) * 4);
    int* tileSum = (int*)alloc((size_t)64 * 4);
    int* tileOff = (int*)alloc((size_t)64 * 4);
    float* part  = (float*)alloc((size_t)NGRAPHS * 3 * POOL_CH * FDIM * 4);
    float* mlp_h = (float*)alloc((size_t)NGRAPHS * MLP_H * 4);

    const int TB = 256;
    int gE = (E + TB - 1) / TB;
    int nTiles = (N + 1023) / 1024;   // 49 for N=50000

    // ---- CSR build ----
    hipMemsetAsync(deg, 0, (size_t)N * 4, stream);
    count_deg_k<<<gE, TB, 0, stream>>>(dst, deg, E);
    gbound_k<<<1, 64, 0, stream>>>(batch, gb, N);
    scan_part_k<<<nTiles, 256, 0, stream>>>(deg, tileSum, N);
    scan_tiles_k<<<1, 64, 0, stream>>>(tileSum, tileOff, nTiles);
    scan_write_k<<<nTiles, 256, 0, stream>>>(deg, tileOff, row_lp, cursor, dinv, N, E);
    scatter_k<<<gE, TB, 0, stream>>>(src, dst, cursor, dinv, elist, E);

    int gGemm = (N + 63) / 64;
    int gWave = (N + 3) / 4;   // 4 node-waves per 256-thread block

    // ---- layer 1 ----
    gemm128x2_k<<<gGemm, 512, 0, stream>>>(x, W_l1, W_r1, bufA, bufB, N);
    gat_pull_k<<<gWave, 256, 0, stream>>>(bufA, bufB, row_lp, elist, att1, b1, bufC, N);
    lp_pull_k<<<gWave, 256, 0, stream>>>(bufC, bufC, bufA, row_lp, elist, dinv, N);
    lp_pull_k<<<gWave, 256, 0, stream>>>(bufC, bufA, bufC, row_lp, elist, dinv, N);

    // ---- layer 2 ----
    gemm128x2_k<<<gGemm, 512, 0, stream>>>(bufC, W_l2, W_r2, bufA, bufB, N);
    gat_pull_k<<<gWave, 256, 0, stream>>>(bufA, bufB, row_lp, elist, att2, b2, bufD, N);
    lp_pull_k<<<gWave, 256, 0, stream>>>(bufD, bufD, bufA, row_lp, elist, dinv, N);
    lp_pull_k<<<gWave, 256, 0, stream>>>(bufD, bufA, bufD, row_lp, elist, dinv, N);

    // ---- pooling (segmented, atomic-free) ----
    pool_part_k<<<dim3(NGRAPHS, 3, POOL_CH), 128, 0, stream>>>(x, bufC, bufD, gb, part);

    // ---- MLP head ----
    mlp1_k<<<NGRAPHS, 256, 0, stream>>>(part, gb, mW1, mb1, mlp_h);
    mlp2_k<<<NGRAPHS, 128, 0, stream>>>(mlp_h, mW2, mb2, out);
}

// Round 9
// 762.257 us; speedup vs baseline: 1.0253x; 1.0253x over previous
//
#include <hip/hip_runtime.h>
#include <math.h>

// ---------------- constants ----------------
#define FDIM 128          // F_IN == HEADS*C_HID == 128
#define NEG_SLOPE 0.2f
#define LP_ALPHA 0.5f
#define NGRAPHS 32
#define POOLF 384         // 3*128
#define MLP_H 256
#define OUT_F 128
#define POOL_CH 8         // chunks per (graph, source) in pooling
#define GCH 16            // gemm k-chunk

#define LRELU(z) ((z) > 0.0f ? (z) : NEG_SLOPE * (z))

// ---------------- CSR build ----------------
__global__ void count_deg_k(const int* __restrict__ dst, int* __restrict__ deg, int E) {
    int e = blockIdx.x * blockDim.x + threadIdx.x;
    if (e < E) atomicAdd(&deg[dst[e]], 1);
}

// ---- hierarchical exclusive scan over deg[N] (tiles of 1024) ----
__global__ __launch_bounds__(256) void scan_part_k(const int* __restrict__ deg,
                                                   int* __restrict__ tileSum, int N) {
    int b = blockIdx.x, t = threadIdx.x;
    int base = b * 1024 + t * 4;
    int v = 0;
    if (base + 3 < N) { int4 d = *(const int4*)(deg + base); v = d.x + d.y + d.z + d.w; }
    else if (base < N) {
        v = deg[base];
        if (base + 1 < N) v += deg[base + 1];
        if (base + 2 < N) v += deg[base + 2];
    }
#pragma unroll
    for (int off = 32; off > 0; off >>= 1) v += __shfl_xor(v, off, 64);
    __shared__ int ws[4];
    if ((t & 63) == 0) ws[t >> 6] = v;
    __syncthreads();
    if (t == 0) tileSum[b] = ws[0] + ws[1] + ws[2] + ws[3];
}

// single wave: exclusive scan of tile sums (nt <= 64)
__global__ void scan_tiles_k(const int* __restrict__ tileSum, int* __restrict__ tileOff, int nt) {
    int t = threadIdx.x;   // 64
    int v = (t < nt) ? tileSum[t] : 0;
    int incl = v;
#pragma unroll
    for (int off = 1; off < 64; off <<= 1) {
        int u = __shfl_up(incl, off, 64);
        if (t >= off) incl += u;
    }
    if (t < nt) tileOff[t] = incl - v;
}

// per-tile write-out of row_ptr + cursor copy (+ fused dinv); row_ptr[N] = E (known)
__global__ __launch_bounds__(256) void scan_write_k(const int* __restrict__ deg,
                                                    const int* __restrict__ tileOff,
                                                    int* __restrict__ row_ptr,
                                                    int* __restrict__ cursor,
                                                    float* __restrict__ dinv, int N, int E) {
    int b = blockIdx.x, t = threadIdx.x;
    int base = b * 1024 + t * 4;
    int d0 = 0, d1 = 0, d2 = 0, d3 = 0;
    if (base + 3 < N) { int4 d = *(const int4*)(deg + base); d0 = d.x; d1 = d.y; d2 = d.z; d3 = d.w; }
    else if (base < N) {
        d0 = deg[base];
        if (base + 1 < N) d1 = deg[base + 1];
        if (base + 2 < N) d2 = deg[base + 2];
    }
    int lsum = d0 + d1 + d2 + d3;
    int lane = t & 63, wv = t >> 6;
    int incl = lsum;
#pragma unroll
    for (int off = 1; off < 64; off <<= 1) {
        int u = __shfl_up(incl, off, 64);
        if (lane >= off) incl += u;
    }
    __shared__ int wsum[4];
    if (lane == 63) wsum[wv] = incl;
    __syncthreads();
    int woff = 0;
#pragma unroll
    for (int k = 0; k < 4; ++k) if (k < wv) woff += wsum[k];
    int off0 = tileOff[b] + woff + (incl - lsum);
    if (base < N)     { row_ptr[base]     = off0;                cursor[base]     = off0;
                        dinv[base]     = d0 > 0 ? 1.0f / sqrtf((float)d0) : 0.0f; }
    if (base + 1 < N) { row_ptr[base + 1] = off0 + d0;           cursor[base + 1] = off0 + d0;
                        dinv[base + 1] = d1 > 0 ? 1.0f / sqrtf((float)d1) : 0.0f; }
    if (base + 2 < N) { row_ptr[base + 2] = off0 + d0 + d1;      cursor[base + 2] = off0 + d0 + d1;
                        dinv[base + 2] = d2 > 0 ? 1.0f / sqrtf((float)d2) : 0.0f; }
    if (base + 3 < N) { row_ptr[base + 3] = off0 + d0 + d1 + d2; cursor[base + 3] = off0 + d0 + d1 + d2;
                        dinv[base + 3] = d3 > 0 ? 1.0f / sqrtf((float)d3) : 0.0f; }
    if (b == 0 && t == 0) row_ptr[N] = E;
}

// one random 8B nt-store per edge: {src, dinv[src]}; cursor gives absolute slot
__global__ void scatter_k(const int* __restrict__ src, const int* __restrict__ dst,
                          int* __restrict__ cursor, const float* __restrict__ dinv,
                          int2* __restrict__ elist, int E) {
    int e = blockIdx.x * blockDim.x + threadIdx.x;
    if (e >= E) return;
    int d = dst[e], s = src[e];
    int pos = atomicAdd(&cursor[d], 1);
    unsigned long long v = (unsigned int)s |
                           ((unsigned long long)(unsigned int)__float_as_int(dinv[s]) << 32);
    __builtin_nontemporal_store(v, (unsigned long long*)&elist[pos]);
}

// ---------------- graph boundaries: batch is SORTED -> binary search ----------------
__global__ void gbound_k(const int* __restrict__ batch, int* __restrict__ gb, int N) {
    int g = threadIdx.x;             // 0..NGRAPHS
    if (g > NGRAPHS) return;
    int lo = 0, hi = N;              // first index with batch[i] >= g
    while (lo < hi) {
        int mid = (lo + hi) >> 1;
        if (batch[mid] < g) lo = mid + 1; else hi = mid;
    }
    gb[g] = lo;
}

// ---------------- fused dual node GEMM: Yl = X@Wl, Yr = X@Wr ----------------
// 64 rows/block, 256 threads, 8x4x2 thread tile. k-chunked (GCH=16): W AND X
// chunks staged in LDS; W read from L2 once per chunk per block (not per k).
// Register prefetch of next chunk overlaps compute.
__global__ __launch_bounds__(256) void gemm128x2_k(const float* __restrict__ X,
                                                   const float* __restrict__ Wl,
                                                   const float* __restrict__ Wr,
                                                   float* __restrict__ Yl,
                                                   float* __restrict__ Yr, int N) {
    __shared__ float Xs[GCH][68];         // [kk][row], 4.35 KB
    __shared__ float Ws[2][GCH][128];     // [mat][kk][col], 16 KB
    int t = threadIdx.x;
    int r0 = blockIdx.x * 64;

    // staging geometry
    int xrow = t >> 2;            // 0..63
    int xk4  = t & 3;             // k-quad within chunk
    int xg   = r0 + xrow;
    // W: idx = t + 256*j over [mat][kr][c4]
    float4 wreg[4];
    float4 xreg;

    auto LOADC = [&](int k0) {
        xreg = (xg < N) ? *(const float4*)(X + (size_t)xg * FDIM + k0 + xk4 * 4)
                        : make_float4(0.f, 0.f, 0.f, 0.f);
#pragma unroll
        for (int j = 0; j < 4; ++j) {
            int idx = t + 256 * j;
            int mat = idx >> 9, kr = (idx >> 5) & 15, c4 = idx & 31;
            const float* Wp = mat ? Wr : Wl;
            wreg[j] = *(const float4*)(Wp + (k0 + kr) * FDIM + c4 * 4);
        }
    };
    auto STOREC = [&]() {
        Xs[xk4 * 4 + 0][xrow] = xreg.x;
        Xs[xk4 * 4 + 1][xrow] = xreg.y;
        Xs[xk4 * 4 + 2][xrow] = xreg.z;
        Xs[xk4 * 4 + 3][xrow] = xreg.w;
#pragma unroll
        for (int j = 0; j < 4; ++j) {
            int idx = t + 256 * j;
            int mat = idx >> 9, kr = (idx >> 5) & 15, c4 = idx & 31;
            *(float4*)(&Ws[mat][kr][c4 * 4]) = wreg[j];
        }
    };

    int tr = t >> 5;      // 0..7  (8 row-groups of 8 rows)
    int tc = t & 31;      // 0..31 (32 col-groups of 4 cols)
    float accl[8][4] = {{0.f}}, accr[8][4] = {{0.f}};

    LOADC(0);
    for (int c = 0; c < FDIM / GCH; ++c) {
        __syncthreads();              // prior compute done reading LDS
        STOREC();
        __syncthreads();              // staged chunk visible
        if (c + 1 < FDIM / GCH) LOADC((c + 1) * GCH);   // prefetch under compute
#pragma unroll
        for (int kk = 0; kk < GCH; ++kk) {
            float4 bl = *(const float4*)(&Ws[0][kk][tc * 4]);
            float4 br = *(const float4*)(&Ws[1][kk][tc * 4]);
            float4 a0 = *(const float4*)(&Xs[kk][tr * 8]);
            float4 a1 = *(const float4*)(&Xs[kk][tr * 8 + 4]);
            float av[8] = {a0.x, a0.y, a0.z, a0.w, a1.x, a1.y, a1.z, a1.w};
#pragma unroll
            for (int r = 0; r < 8; ++r) {
                accl[r][0] = fmaf(av[r], bl.x, accl[r][0]);
                accl[r][1] = fmaf(av[r], bl.y, accl[r][1]);
                accl[r][2] = fmaf(av[r], bl.z, accl[r][2]);
                accl[r][3] = fmaf(av[r], bl.w, accl[r][3]);
                accr[r][0] = fmaf(av[r], br.x, accr[r][0]);
                accr[r][1] = fmaf(av[r], br.y, accr[r][1]);
                accr[r][2] = fmaf(av[r], br.z, accr[r][2]);
                accr[r][3] = fmaf(av[r], br.w, accr[r][3]);
            }
        }
    }
#pragma unroll
    for (int r = 0; r < 8; ++r) {
        int row = r0 + tr * 8 + r;
        if (row < N) {
            *(float4*)(Yl + (size_t)row * FDIM + tc * 4) =
                make_float4(accl[r][0], accl[r][1], accl[r][2], accl[r][3]);
            *(float4*)(Yr + (size_t)row * FDIM + tc * 4) =
                make_float4(accr[r][0], accr[r][1], accr[r][2], accr[r][3]);
        }
    }
}

// ---------------- GATv2 pull: quarter-wave edge groups ----------------
// wave = 1 node. qw = lane>>4 (4 edge streams), lq = lane&15 holds channels
// [8lq, 8lq+8) as 2 float4 (lq<8 -> head0, lq>=8 -> head1). Head-logit reduce
// = 3 shfls within 8-lane groups. 8 edges in flight (4 quarters x 2 states).
// Merge: in-lane, then butterfly shfl_xor 16/32 (softmax segment merges).
__global__ __launch_bounds__(256) void gat_pull_k(const float* __restrict__ xl,
                                                  const float* __restrict__ xr,
                                                  const int* __restrict__ row_ptr,
                                                  const int2* __restrict__ elist,
                                                  const float* __restrict__ att,
                                                  const float* __restrict__ bias,
                                                  float* __restrict__ out, int N) {
    int wid = threadIdx.x >> 6;
    int lane = threadIdx.x & 63;
    int qw = lane >> 4;
    int lq = lane & 15;
    int i = blockIdx.x * 4 + wid;
    if (i >= N) return;
    int cbase = 8 * lq;
    float4 at0 = *(const float4*)(att + cbase);
    float4 at1 = *(const float4*)(att + cbase + 4);
    size_t ibase = (size_t)i * FDIM + cbase;
    float4 xr0 = *(const float4*)(xr + ibase);
    float4 xr1 = *(const float4*)(xr + ibase + 4);
    float4 xs0 = *(const float4*)(xl + ibase);
    float4 xs1 = *(const float4*)(xl + ibase + 4);

    auto qdot = [&](float4 x0, float4 x1) {   // this head's logit (8-lane reduce)
        float v = LRELU(xr0.x + x0.x) * at0.x + LRELU(xr0.y + x0.y) * at0.y
                + LRELU(xr0.z + x0.z) * at0.z + LRELU(xr0.w + x0.w) * at0.w
                + LRELU(xr1.x + x1.x) * at1.x + LRELU(xr1.y + x1.y) * at1.y
                + LRELU(xr1.z + x1.z) * at1.z + LRELU(xr1.w + x1.w) * at1.w;
        v += __shfl_xor(v, 1, 64);
        v += __shfl_xor(v, 2, 64);
        v += __shfl_xor(v, 4, 64);
        return v;
    };

    const float4 z4 = make_float4(0.f, 0.f, 0.f, 0.f);
    // self-loop seeds quarter 0's state A
    float lself = qdot(xs0, xs1);
    bool q0 = (qw == 0);
    float mA = q0 ? lself : -INFINITY, sA = q0 ? 1.0f : 0.0f;
    float4 aA0 = q0 ? xs0 : z4, aA1 = q0 ? xs1 : z4;
    float mB = -INFINITY, sB = 0.0f;
    float4 aB0 = z4, aB1 = z4;

    int beg = row_ptr[i], end = row_ptr[i + 1];
    for (int p = beg; p < end; p += 8) {
        int i0 = p + qw, i1 = p + 4 + qw;
        bool v0 = i0 < end, v1 = i1 < end;
        int j0 = elist[min(i0, end - 1)].x;
        int j1 = elist[min(i1, end - 1)].x;
        const float* b0 = xl + (size_t)j0 * FDIM + cbase;
        const float* b1 = xl + (size_t)j1 * FDIM + cbase;
        float4 x00 = *(const float4*)(b0), x01 = *(const float4*)(b0 + 4);
        float4 x10 = *(const float4*)(b1), x11 = *(const float4*)(b1 + 4);
        float l0 = qdot(x00, x01);
        float l1 = qdot(x10, x11);
        if (v0) {
            float mn = fmaxf(mA, l0);
            float sc = __expf(mA - mn), pe = __expf(l0 - mn);  // mA=-inf -> sc=0
            sA = fmaf(sA, sc, pe);
            aA0.x = fmaf(aA0.x, sc, pe * x00.x); aA0.y = fmaf(aA0.y, sc, pe * x00.y);
            aA0.z = fmaf(aA0.z, sc, pe * x00.z); aA0.w = fmaf(aA0.w, sc, pe * x00.w);
            aA1.x = fmaf(aA1.x, sc, pe * x01.x); aA1.y = fmaf(aA1.y, sc, pe * x01.y);
            aA1.z = fmaf(aA1.z, sc, pe * x01.z); aA1.w = fmaf(aA1.w, sc, pe * x01.w);
            mA = mn;
        }
        if (v1) {
            float mn = fmaxf(mB, l1);
            float sc = __expf(mB - mn), pe = __expf(l1 - mn);
            sB = fmaf(sB, sc, pe);
            aB0.x = fmaf(aB0.x, sc, pe * x10.x); aB0.y = fmaf(aB0.y, sc, pe * x10.y);
            aB0.z = fmaf(aB0.z, sc, pe * x10.z); aB0.w = fmaf(aB0.w, sc, pe * x10.w);
            aB1.x = fmaf(aB1.x, sc, pe * x11.x); aB1.y = fmaf(aB1.y, sc, pe * x11.y);
            aB1.z = fmaf(aB1.z, sc, pe * x11.z); aB1.w = fmaf(aB1.w, sc, pe * x11.w);
            mB = mn;
        }
    }
    // in-lane merge B -> A (guard double -inf)
    {
        float mn = fmaxf(mA, mB);
        float cA = (mA == -INFINITY) ? 0.0f : __expf(mA - mn);
        float cB = (mB == -INFINITY) ? 0.0f : __expf(mB - mn);
        sA = sA * cA + sB * cB;
        aA0.x = aA0.x * cA + aB0.x * cB; aA0.y = aA0.y * cA + aB0.y * cB;
        aA0.z = aA0.z * cA + aB0.z * cB; aA0.w = aA0.w * cA + aB0.w * cB;
        aA1.x = aA1.x * cA + aB1.x * cB; aA1.y = aA1.y * cA + aB1.y * cB;
        aA1.z = aA1.z * cA + aB1.z * cB; aA1.w = aA1.w * cA + aB1.w * cB;
        mA = mn;
    }
    // butterfly across quarters (xor 16, then 32); same lq -> same head
#pragma unroll
    for (int mask = 16; mask <= 32; mask <<= 1) {
        float pm = __shfl_xor(mA, mask, 64);
        float ps = __shfl_xor(sA, mask, 64);
        float p0x = __shfl_xor(aA0.x, mask, 64), p0y = __shfl_xor(aA0.y, mask, 64);
        float p0z = __shfl_xor(aA0.z, mask, 64), p0w = __shfl_xor(aA0.w, mask, 64);
        float p1x = __shfl_xor(aA1.x, mask, 64), p1y = __shfl_xor(aA1.y, mask, 64);
        float p1z = __shfl_xor(aA1.z, mask, 64), p1w = __shfl_xor(aA1.w, mask, 64);
        float mn = fmaxf(mA, pm);
        float cA = (mA == -INFINITY) ? 0.0f : __expf(mA - mn);
        float cP = (pm == -INFINITY) ? 0.0f : __expf(pm - mn);
        sA = sA * cA + ps * cP;
        aA0.x = aA0.x * cA + p0x * cP; aA0.y = aA0.y * cA + p0y * cP;
        aA0.z = aA0.z * cA + p0z * cP; aA0.w = aA0.w * cA + p0w * cP;
        aA1.x = aA1.x * cA + p1x * cP; aA1.y = aA1.y * cA + p1y * cP;
        aA1.z = aA1.z * cA + p1z * cP; aA1.w = aA1.w * cA + p1w * cP;
        mA = mn;
    }
    if (qw == 0) {
        float inv = 1.0f / (sA + 1e-16f);
        float4 bv0 = *(const float4*)(bias + cbase);
        float4 bv1 = *(const float4*)(bias + cbase + 4);
        float z0 = aA0.x * inv + bv0.x, z1 = aA0.y * inv + bv0.y;
        float z2 = aA0.z * inv + bv0.z, z3 = aA0.w * inv + bv0.w;
        float z4_ = aA1.x * inv + bv1.x, z5 = aA1.y * inv + bv1.y;
        float z6 = aA1.z * inv + bv1.z, z7 = aA1.w * inv + bv1.w;
        float4 o0, o1;
        o0.x = (z0 > 0.f) ? z0 : (__expf(z0) - 1.f);
        o0.y = (z1 > 0.f) ? z1 : (__expf(z1) - 1.f);
        o0.z = (z2 > 0.f) ? z2 : (__expf(z2) - 1.f);
        o0.w = (z3 > 0.f) ? z3 : (__expf(z3) - 1.f);
        o1.x = (z4_ > 0.f) ? z4_ : (__expf(z4_) - 1.f);
        o1.y = (z5 > 0.f) ? z5 : (__expf(z5) - 1.f);
        o1.z = (z6 > 0.f) ? z6 : (__expf(z6) - 1.f);
        o1.w = (z7 > 0.f) ? z7 : (__expf(z7) - 1.f);
        *(float4*)(out + ibase) = o0;
        *(float4*)(out + ibase + 4) = o1;
    }
}

// ---------------- label propagation pull: half-wave edge pairing ----------------
__global__ __launch_bounds__(256) void lp_pull_k(const float* __restrict__ y,
                                                 const float* __restrict__ cur,
                                                 float* __restrict__ nxt,
                                                 const int* __restrict__ row_ptr,
                                                 const int2* __restrict__ elist,
                                                 const float* __restrict__ dinv, int N) {
    int wid = threadIdx.x >> 6, lane = threadIdx.x & 63;
    int half = lane >> 5, lh = lane & 31;
    int i = blockIdx.x * 4 + wid;
    if (i >= N) return;
    int beg = row_ptr[i], end = row_ptr[i + 1];
    float4 a0 = make_float4(0.f, 0.f, 0.f, 0.f), a1 = a0, a2 = a0, a3 = a0;
    for (int p = beg; p < end; p += 8) {
        int i0 = p + half, i1 = p + 2 + half, i2 = p + 4 + half, i3 = p + 6 + half;
        int2 e0 = elist[min(i0, end - 1)];
        int2 e1 = elist[min(i1, end - 1)];
        int2 e2 = elist[min(i2, end - 1)];
        int2 e3 = elist[min(i3, end - 1)];
        float w0 = (i0 < end) ? __int_as_float(e0.y) : 0.0f;
        float w1 = (i1 < end) ? __int_as_float(e1.y) : 0.0f;
        float w2 = (i2 < end) ? __int_as_float(e2.y) : 0.0f;
        float w3 = (i3 < end) ? __int_as_float(e3.y) : 0.0f;
        float4 x0 = *(const float4*)(cur + (size_t)e0.x * FDIM + 4 * lh);
        float4 x1 = *(const float4*)(cur + (size_t)e1.x * FDIM + 4 * lh);
        float4 x2 = *(const float4*)(cur + (size_t)e2.x * FDIM + 4 * lh);
        float4 x3 = *(const float4*)(cur + (size_t)e3.x * FDIM + 4 * lh);
        a0.x = fmaf(w0, x0.x, a0.x); a0.y = fmaf(w0, x0.y, a0.y);
        a0.z = fmaf(w0, x0.z, a0.z); a0.w = fmaf(w0, x0.w, a0.w);
        a1.x = fmaf(w1, x1.x, a1.x); a1.y = fmaf(w1, x1.y, a1.y);
        a1.z = fmaf(w1, x1.z, a1.z); a1.w = fmaf(w1, x1.w, a1.w);
        a2.x = fmaf(w2, x2.x, a2.x); a2.y = fmaf(w2, x2.y, a2.y);
        a2.z = fmaf(w2, x2.z, a2.z); a2.w = fmaf(w2, x2.w, a2.w);
        a3.x = fmaf(w3, x3.x, a3.x); a3.y = fmaf(w3, x3.y, a3.y);
        a3.z = fmaf(w3, x3.z, a3.z); a3.w = fmaf(w3, x3.w, a3.w);
    }
    float4 a;
    a.x = (a0.x + a1.x) + (a2.x + a3.x);
    a.y = (a0.y + a1.y) + (a2.y + a3.y);
    a.z = (a0.z + a1.z) + (a2.z + a3.z);
    a.w = (a0.w + a1.w) + (a2.w + a3.w);
    a.x += __shfl_xor(a.x, 32, 64);
    a.y += __shfl_xor(a.y, 32, 64);
    a.z += __shfl_xor(a.z, 32, 64);
    a.w += __shfl_xor(a.w, 32, 64);
    if (half == 0) {
        float di = dinv[i];
        size_t ibase = (size_t)i * FDIM + 4 * lh;
        float4 yv = *(const float4*)(y + ibase);
        float4 o;
        o.x = fminf(fmaxf(fmaf(LP_ALPHA * di, a.x, (1.0f - LP_ALPHA) * yv.x), 0.f), 1.f);
        o.y = fminf(fmaxf(fmaf(LP_ALPHA * di, a.y, (1.0f - LP_ALPHA) * yv.y), 0.f), 1.f);
        o.z = fminf(fmaxf(fmaf(LP_ALPHA * di, a.z, (1.0f - LP_ALPHA) * yv.z), 0.f), 1.f);
        o.w = fminf(fmaxf(fmaf(LP_ALPHA * di, a.w, (1.0f - LP_ALPHA) * yv.w), 0.f), 1.f);
        *(float4*)(nxt + ibase) = o;
    }
}

// ---------------- pooling: segmented (batch sorted), atomic-free ----------------
__global__ void pool_part_k(const float* __restrict__ x, const float* __restrict__ h1,
                            const float* __restrict__ h2, const int* __restrict__ gb,
                            float* __restrict__ part) {
    int g = blockIdx.x, si = blockIdx.y, ch = blockIdx.z;
    int t = threadIdx.x; // 128
    const float* s = (si == 0) ? x : ((si == 1) ? h1 : h2);
    int n0g = gb[g], n1g = gb[g + 1];
    int len = n1g - n0g;
    int per = (len + POOL_CH - 1) / POOL_CH;
    int n0 = n0g + ch * per;
    int n1 = min(n0 + per, n1g);
    float acc = 0.0f;
    for (int n = n0; n < n1; ++n) acc += s[(size_t)n * FDIM + t];
    part[(((g * 3 + si) << 3) + ch) * FDIM + t] = acc;
}

// ---------------- MLP ----------------
__global__ void mlp1_k(const float* __restrict__ part, const int* __restrict__ gb,
                       const float* __restrict__ W1, const float* __restrict__ b1,
                       float* __restrict__ h) {
    int g = blockIdx.x;     // 32
    int t = threadIdx.x;    // 256
    __shared__ float gm[POOLF];
    int cnt = gb[g + 1] - gb[g];
    float inv = 1.0f / fmaxf((float)cnt, 1.0f);
    for (int f = t; f < POOLF; f += 256) {
        int si = f >> 7, fl = f & 127;
        float s = 0.0f;
#pragma unroll
        for (int c = 0; c < POOL_CH; ++c)
            s += part[(((g * 3 + si) << 3) + c) * FDIM + fl];
        gm[f] = s * inv;
    }
    __syncthreads();
    float acc = b1[t];
    for (int k = 0; k < POOLF; ++k) acc = fmaf(gm[k], W1[k * MLP_H + t], acc);
    h[g * MLP_H + t] = fmaxf(acc, 0.0f);
}

__global__ void mlp2_k(const float* __restrict__ h, const float* __restrict__ W2,
                       const float* __restrict__ b2, float* __restrict__ out) {
    int g = blockIdx.x;     // 32
    int t = threadIdx.x;    // 128
    __shared__ float hs[MLP_H];
    for (int k = t; k < MLP_H; k += 128) hs[k] = h[g * MLP_H + k];
    __syncthreads();
    float acc = b2[t];
    for (int k = 0; k < MLP_H; ++k) acc = fmaf(hs[k], W2[k * OUT_F + t], acc);
    out[g * OUT_F + t] = acc;
}

// ---------------- launch ----------------
extern "C" void kernel_launch(void* const* d_in, const int* in_sizes, int n_in,
                              void* d_out, int out_size, void* d_ws, size_t ws_size,
                              hipStream_t stream) {
    const float* x    = (const float*)d_in[0];
    const int*   ei   = (const int*)d_in[1];
    const int*   batch= (const int*)d_in[2];
    const float* W_l1 = (const float*)d_in[3];
    const float* W_r1 = (const float*)d_in[4];
    const float* att1 = (const float*)d_in[5];
    const float* b1   = (const float*)d_in[6];
    const float* W_l2 = (const float*)d_in[7];
    const float* W_r2 = (const float*)d_in[8];
    const float* att2 = (const float*)d_in[9];
    const float* b2   = (const float*)d_in[10];
    const float* mW1  = (const float*)d_in[11];
    const float* mb1  = (const float*)d_in[12];
    const float* mW2  = (const float*)d_in[13];
    const float* mb2  = (const float*)d_in[14];
    float* out = (float*)d_out;

    const int N = in_sizes[2];
    const int E = in_sizes[1] / 2;
    const int* src = ei;
    const int* dst = ei + E;

    char* w = (char*)d_ws;
    auto alloc = [&](size_t bytes) -> char* {
        char* p = w;
        w += (bytes + 255) & ~(size_t)255;
        return p;
    };
    float* bufA = (float*)alloc((size_t)N * FDIM * 4);
    float* bufB = (float*)alloc((size_t)N * FDIM * 4);
    float* bufC = (float*)alloc((size_t)N * FDIM * 4);   // h1 lives here
    float* bufD = (float*)alloc((size_t)N * FDIM * 4);   // h2 lives here
    int* deg     = (int*)alloc((size_t)N * 4);
    int* cursor  = (int*)alloc((size_t)N * 4);
    int* row_lp  = (int*)alloc((size_t)(N + 1) * 4);
    int2* elist  = (int2*)alloc((size_t)E * 8);
    float* dinv  = (float*)alloc((size_t)N * 4);
    int* gb      = (int*)alloc((size_t)(NGRAPHS + 1) * 4);
    int* tileSum = (int*)alloc((size_t)64 * 4);
    int* tileOff = (int*)alloc((size_t)64 * 4);
    float* part  = (float*)alloc((size_t)NGRAPHS * 3 * POOL_CH * FDIM * 4);
    float* mlp_h = (float*)alloc((size_t)NGRAPHS * MLP_H * 4);

    const int TB = 256;
    int gE = (E + TB - 1) / TB;
    int nTiles = (N + 1023) / 1024;   // 49 for N=50000

    // ---- CSR build ----
    hipMemsetAsync(deg, 0, (size_t)N * 4, stream);
    count_deg_k<<<gE, TB, 0, stream>>>(dst, deg, E);
    gbound_k<<<1, 64, 0, stream>>>(batch, gb, N);
    scan_part_k<<<nTiles, 256, 0, stream>>>(deg, tileSum, N);
    scan_tiles_k<<<1, 64, 0, stream>>>(tileSum, tileOff, nTiles);
    scan_write_k<<<nTiles, 256, 0, stream>>>(deg, tileOff, row_lp, cursor, dinv, N, E);
    scatter_k<<<gE, TB, 0, stream>>>(src, dst, cursor, dinv, elist, E);

    int gGemm = (N + 63) / 64;
    int gWave = (N + 3) / 4;   // 4 node-waves per 256-thread block

    // ---- layer 1 ----
    gemm128x2_k<<<gGemm, 256, 0, stream>>>(x, W_l1, W_r1, bufA, bufB, N);
    gat_pull_k<<<gWave, 256, 0, stream>>>(bufA, bufB, row_lp, elist, att1, b1, bufC, N);
    lp_pull_k<<<gWave, 256, 0, stream>>>(bufC, bufC, bufA, row_lp, elist, dinv, N);
    lp_pull_k<<<gWave, 256, 0, stream>>>(bufC, bufA, bufC, row_lp, elist, dinv, N);

    // ---- layer 2 ----
    gemm128x2_k<<<gGemm, 256, 0, stream>>>(bufC, W_l2, W_r2, bufA, bufB, N);
    gat_pull_k<<<gWave, 256, 0, stream>>>(bufA, bufB, row_lp, elist, att2, b2, bufD, N);
    lp_pull_k<<<gWave, 256, 0, stream>>>(bufD, bufD, bufA, row_lp, elist, dinv, N);
    lp_pull_k<<<gWave, 256, 0, stream>>>(bufD, bufA, bufD, row_lp, elist, dinv, N);

    // ---- pooling (segmented, atomic-free) ----
    pool_part_k<<<dim3(NGRAPHS, 3, POOL_CH), 128, 0, stream>>>(x, bufC, bufD, gb, part);

    // ---- MLP head ----
    mlp1_k<<<NGRAPHS, 256, 0, stream>>>(part, gb, mW1, mb1, mlp_h);
    mlp2_k<<<NGRAPHS, 128, 0, stream>>>(mlp_h, mW2, mb2, out);
}